// Round 7
// baseline (198.075 us; speedup 1.0000x reference)
//
#include <hip/hip_runtime.h>

// E = sum over 4 directional diffs squared of avgpool4(mean_c(org - enhance)).
// R7: maximize read linearity. Kernel 1: one block per (b, channel, 16-row
// group); it reads TWO contiguous 32 KB runs (org + enh, nontemporal), pools
// 4x4, writes per-channel pooled diff maps pc[b][c][128][128] to ws (6 MB).
// Evidence: R6's 12-runs-per-block layout reads at ~3.5 TB/s while the
// harness's linear fill writes at 6.7 TB/s and linear-streaming RMSNorm
// (m146) reads at 4.9 TB/s -> stream count / DRAM-page locality suspect.
// Kernel 2: fused channel-combine + 5-point stencil from the L2-resident
// maps (15 loads/pixel, ~31 MB L2 traffic), writes E.

typedef float f4 __attribute__((ext_vector_type(4)));

__global__ __launch_bounds__(256) void pool_channel_kernel(
    const f4* __restrict__ org, const f4* __restrict__ enh,
    float* __restrict__ pc) {
  __shared__ float red[4][128];
  int t = threadIdx.x;
  int s = blockIdx.x;                 // s = (b*3 + c)*32 + g
  int g  = s & 31;                    // 16-row group (4 pooled rows)
  int bc = s >> 5;                    // b*3 + c
  // float4 units: one channel row = 128 float4; group base:
  int base = bc * 65536 + g * 2048;   // contiguous 32 KB run per array

  int h  = t >> 7;                    // row parity within 2-row chunk
  int px = t & 127;                   // pooled column (one float4 = 4 cols)

  // 16 independent nt loads issued up front (8 org + 8 enh).
  int j = base + t;
  f4 o0 = __builtin_nontemporal_load(&org[j +    0]);
  f4 o1 = __builtin_nontemporal_load(&org[j +  256]);
  f4 o2 = __builtin_nontemporal_load(&org[j +  512]);
  f4 o3 = __builtin_nontemporal_load(&org[j +  768]);
  f4 o4 = __builtin_nontemporal_load(&org[j + 1024]);
  f4 o5 = __builtin_nontemporal_load(&org[j + 1280]);
  f4 o6 = __builtin_nontemporal_load(&org[j + 1536]);
  f4 o7 = __builtin_nontemporal_load(&org[j + 1792]);
  f4 e0 = __builtin_nontemporal_load(&enh[j +    0]);
  f4 e1 = __builtin_nontemporal_load(&enh[j +  256]);
  f4 e2 = __builtin_nontemporal_load(&enh[j +  512]);
  f4 e3 = __builtin_nontemporal_load(&enh[j +  768]);
  f4 e4 = __builtin_nontemporal_load(&enh[j + 1024]);
  f4 e5 = __builtin_nontemporal_load(&enh[j + 1280]);
  f4 e6 = __builtin_nontemporal_load(&enh[j + 1536]);
  f4 e7 = __builtin_nontemporal_load(&enh[j + 1792]);

  f4 d0 = (o0 - e0) + (o1 - e1);      // pooled row 0: chunks k=0,1
  f4 d1 = (o2 - e2) + (o3 - e3);      // pooled row 1: chunks k=2,3
  f4 d2 = (o4 - e4) + (o5 - e5);      // pooled row 2
  f4 d3 = (o6 - e6) + (o7 - e7);      // pooled row 3
  float a0 = d0.x + d0.y + d0.z + d0.w;
  float a1 = d1.x + d1.y + d1.z + d1.w;
  float a2 = d2.x + d2.y + d2.z + d2.w;
  float a3 = d3.x + d3.y + d3.z + d3.w;

  if (h == 1) {
    red[0][px] = a0; red[1][px] = a1; red[2][px] = a2; red[3][px] = a3;
  }
  __syncthreads();
  if (h == 0) {
    int ob = bc * 16384 + g * 4 * 128 + px;   // per-channel pooled map
    pc[ob +   0] = a0 + red[0][px];
    pc[ob + 128] = a1 + red[1][px];
    pc[ob + 256] = a2 + red[2][px];
    pc[ob + 384] = a3 + red[3][px];
  }
}

__global__ __launch_bounds__(256) void combine_stencil_kernel(
    const float* __restrict__ pc, float* __restrict__ out) {
  int idx = blockIdx.x * 256 + threadIdx.x;   // = b*16384 + y*128 + x
  int x = idx & 127;
  int y = (idx >> 7) & 127;
  int b = idx >> 14;
  const float* m0 = pc + (b * 3 + 0) * 16384;
  const float* m1 = pc + (b * 3 + 1) * 16384;
  const float* m2 = pc + (b * 3 + 2) * 16384;
  int o = y * 128 + x;
  auto P = [&](int oo) {
    return (m0[oo] + m1[oo] + m2[oo]) * (1.0f / 48.0f);
  };
  float c = P(o);
  float l = (x > 0)   ? P(o - 1)   : 0.f;
  float r = (x < 127) ? P(o + 1)   : 0.f;
  float u = (y > 0)   ? P(o - 128) : 0.f;
  float d = (y < 127) ? P(o + 128) : 0.f;
  float dl = c - l, dr = c - r, du = c - u, dd = c - d;
  out[idx] = dl * dl + dr * dr + du * du + dd * dd;
}

extern "C" void kernel_launch(void* const* d_in, const int* in_sizes, int n_in,
                              void* d_out, int out_size, void* d_ws, size_t ws_size,
                              hipStream_t stream) {
  const f4* org = (const f4*)d_in[0];
  const f4* enh = (const f4*)d_in[1];
  float* pc  = (float*)d_ws;       // 32*3*128*128 floats = 6 MB scratch
  float* out = (float*)d_out;      // 32*1*128*128 floats

  pool_channel_kernel<<<32 * 3 * 32, 256, 0, stream>>>(org, enh, pc);
  const int N = 32 * 128 * 128;
  combine_stencil_kernel<<<N / 256, 256, 0, stream>>>(pc, out);
}